// Round 1
// baseline (962.172 us; speedup 1.0000x reference)
//
#include <hip/hip_runtime.h>
#include <stdint.h>

#define NB 4096
#define NS 512
#define NA 64
#define NH1 1024
#define NH2 512

typedef __attribute__((ext_vector_type(8))) short bf16x8;
typedef __attribute__((ext_vector_type(4))) float f32x4;

__device__ __forceinline__ unsigned short f2bf(float f) {
    union { float f; unsigned u; } v; v.f = f;
    return (unsigned short)((v.u + 0x8000u) >> 16);   // round-half-up bf16
}
__device__ __forceinline__ float bf2f(unsigned short h) {
    union { float f; unsigned u; } v; v.u = ((unsigned)h) << 16;
    return v.f;
}
__device__ __forceinline__ unsigned pack2bf(float lo, float hi) {
    union { float f; unsigned u; } a, b; a.f = lo; b.f = hi;
    unsigned l = (a.u + 0x8000u) >> 16;
    unsigned h = (b.u + 0x8000u) & 0xFFFF0000u;
    return h | l;
}
__device__ __forceinline__ void split2(float x, unsigned short& h, unsigned short& l) {
    unsigned short hh = f2bf(x);
    h = hh;
    l = f2bf(x - bf2f(hh));
}

// ---------------- P0: invn[b] = 1/(sqrt(||s_b||^2 + 1) + 1e-8) ----------------
__global__ void knorm(const float* __restrict__ S, float* __restrict__ invn) {
    int b = blockIdx.x; int l = threadIdx.x; // 64 threads (one wave)
    const float* row = S + b * NS;
    float s = 0.f;
    for (int k = l; k < NS; k += 64) { float v = row[k]; s = fmaf(v, v, s); }
    for (int off = 32; off; off >>= 1) s += __shfl_down(s, off, 64);
    if (l == 0) invn[b] = 1.0f / (sqrtf(s + 1.0f) + 1e-8f);
}

// ---------------- P1: W2 -> bf16, caT[a][o] = W1[o, 512+a] ----------------
__global__ void kprep(const float* __restrict__ W1, const float* __restrict__ W2,
                      unsigned short* __restrict__ W2h, float* __restrict__ caT) {
    int i = blockIdx.x * 256 + threadIdx.x;
    if (i < NH2 * NH1) {
        W2h[i] = f2bf(W2[i]);
    } else {
        int j = i - NH2 * NH1; // 0..65535
        int a = j >> 10, o = j & 1023;
        caT[j] = W1[o * 576 + 512 + a];
    }
}

// ---------------- P2: G[b][o] = (states @ W1s^T)*invn_b + b1  (split-bf16, 3 GEMMs) ----
__global__ __launch_bounds__(256) void kgemm1(
        const float* __restrict__ Sm, const float* __restrict__ W1,
        const float* __restrict__ b1, const float* __restrict__ invn,
        float* __restrict__ G) {
    // M=4096(b) x N=1024(o), K=512. 128x128 tiles -> 32x8 = 256 blocks.
    const int m0 = (blockIdx.x >> 3) * 128;
    const int n0 = (blockIdx.x & 7) * 128;
    __shared__ unsigned short Ah[128][40], Al[128][40], Bh[128][40], Bl[128][40];
    int t = threadIdx.x;
    int lane = t & 63, wave = t >> 6;
    int wr = wave >> 1, wc = wave & 1;
    int qd = lane >> 4, cl = lane & 15;
    int r = t >> 1, seg = t & 1;
    f32x4 acc[4][4] = {};

    for (int k0 = 0; k0 < 512; k0 += 32) {
        { // stage + hi/lo split: A rows from states, B rows from W1 (stride 576)
            const float4* as4 = (const float4*)(Sm + (size_t)(m0 + r) * NS + k0 + seg * 16);
            const float4* bs4 = (const float4*)(W1 + (size_t)(n0 + r) * 576 + k0 + seg * 16);
            unsigned* ah = (unsigned*)&Ah[r][seg * 16];
            unsigned* al = (unsigned*)&Al[r][seg * 16];
            unsigned* bh = (unsigned*)&Bh[r][seg * 16];
            unsigned* bl = (unsigned*)&Bl[r][seg * 16];
#pragma unroll
            for (int v = 0; v < 4; v++) {
                float4 fa = as4[v];
                unsigned short h0,h1,h2,h3,l0,l1,l2,l3;
                split2(fa.x,h0,l0); split2(fa.y,h1,l1); split2(fa.z,h2,l2); split2(fa.w,h3,l3);
                ah[v*2]   = (unsigned)h0 | ((unsigned)h1 << 16);
                ah[v*2+1] = (unsigned)h2 | ((unsigned)h3 << 16);
                al[v*2]   = (unsigned)l0 | ((unsigned)l1 << 16);
                al[v*2+1] = (unsigned)l2 | ((unsigned)l3 << 16);
                float4 fb = bs4[v];
                split2(fb.x,h0,l0); split2(fb.y,h1,l1); split2(fb.z,h2,l2); split2(fb.w,h3,l3);
                bh[v*2]   = (unsigned)h0 | ((unsigned)h1 << 16);
                bh[v*2+1] = (unsigned)h2 | ((unsigned)h3 << 16);
                bl[v*2]   = (unsigned)l0 | ((unsigned)l1 << 16);
                bl[v*2+1] = (unsigned)l2 | ((unsigned)l3 << 16);
            }
        }
        __syncthreads();
        bf16x8 a_h[4], a_l[4], b_h[4], b_l[4];
#pragma unroll
        for (int mt = 0; mt < 4; mt++) {
            a_h[mt] = *(const bf16x8*)&Ah[wr*64 + mt*16 + cl][qd*8];
            a_l[mt] = *(const bf16x8*)&Al[wr*64 + mt*16 + cl][qd*8];
        }
#pragma unroll
        for (int nt = 0; nt < 4; nt++) {
            b_h[nt] = *(const bf16x8*)&Bh[wc*64 + nt*16 + cl][qd*8];
            b_l[nt] = *(const bf16x8*)&Bl[wc*64 + nt*16 + cl][qd*8];
        }
#pragma unroll
        for (int mt = 0; mt < 4; mt++)
#pragma unroll
            for (int nt = 0; nt < 4; nt++) {
                acc[mt][nt] = __builtin_amdgcn_mfma_f32_16x16x32_bf16(a_h[mt], b_h[nt], acc[mt][nt], 0, 0, 0);
                acc[mt][nt] = __builtin_amdgcn_mfma_f32_16x16x32_bf16(a_h[mt], b_l[nt], acc[mt][nt], 0, 0, 0);
                acc[mt][nt] = __builtin_amdgcn_mfma_f32_16x16x32_bf16(a_l[mt], b_h[nt], acc[mt][nt], 0, 0, 0);
            }
        __syncthreads();
    }
    // epilogue: G = acc*invn[b] + b1[o]  (C/D layout: col=lane&15, row=quad*4+i)
#pragma unroll
    for (int mt = 0; mt < 4; mt++)
#pragma unroll
        for (int i = 0; i < 4; i++) {
            int m = m0 + wr*64 + mt*16 + qd*4 + i;
            float iv = invn[m];
#pragma unroll
            for (int nt = 0; nt < 4; nt++) {
                int n = n0 + wc*64 + nt*16 + cl;
                G[(size_t)m * NH1 + n] = fmaf(acc[mt][nt][i], iv, b1[n]);
            }
        }
}

// ---------------- Main: per (a,b) row: h1=relu(G+ca*invn) -> [norm] -> W2 -> relu -> Wq ----
__global__ __launch_bounds__(256) void kmain(
        const float* __restrict__ G, const float* __restrict__ caT,
        const unsigned short* __restrict__ W2h, const float* __restrict__ invn,
        const float* __restrict__ b2, const float* __restrict__ Wq,
        const float* __restrict__ bq, float* __restrict__ out) {
    // grid: 8192 = 512 btile x 4 atile x 4 colblk ; row-tile = 16 actions x 8 b
    int bid = blockIdx.x;
    int colblk = bid & 3;
    int rt = bid >> 2;
    int atile = rt & 3;
    int btile = rt >> 2;
    const int n0 = colblk * 128;

    __shared__ unsigned short As[128][72];
    __shared__ unsigned short Bs[128][72];
    __shared__ float red[256];
    __shared__ float invnh[128];
    __shared__ float qred[128][2];

    int t = threadIdx.x;
    int lane = t & 63, wave = t >> 6;
    int wr = wave >> 1, wc = wave & 1;
    int qd = lane >> 4, cl = lane & 15;

    // A-gen mapping: thread pair per row; row m = a_local*8 + b_local
    int rowm = t >> 1, seg = t & 1;
    int aidx = atile * 16 + (rowm >> 3);
    int bidx = btile * 8 + (rowm & 7);
    float inv_b = invn[bidx];
    const float* grow = G + (size_t)bidx * NH1;
    const float* crow = caT + (size_t)aidx * NH1;

    float sq = 0.f;
    f32x4 acc[4][4] = {};

    for (int k0 = 0; k0 < NH1; k0 += 64) {
        { // A-gen: h1 = relu(G + ca*invn), accumulate h1^2, pack bf16 into LDS
            const float4* gp = (const float4*)(grow + k0 + seg * 32);
            const float4* cp = (const float4*)(crow + k0 + seg * 32);
            unsigned* dst = (unsigned*)&As[rowm][seg * 32];
#pragma unroll
            for (int v = 0; v < 8; v += 2) {
                float4 g0 = gp[v],   c0 = cp[v];
                float4 g1 = gp[v+1], c1 = cp[v+1];
                float h0 = fmaxf(fmaf(c0.x, inv_b, g0.x), 0.f);
                float h1 = fmaxf(fmaf(c0.y, inv_b, g0.y), 0.f);
                float h2 = fmaxf(fmaf(c0.z, inv_b, g0.z), 0.f);
                float h3 = fmaxf(fmaf(c0.w, inv_b, g0.w), 0.f);
                float h4 = fmaxf(fmaf(c1.x, inv_b, g1.x), 0.f);
                float h5 = fmaxf(fmaf(c1.y, inv_b, g1.y), 0.f);
                float h6 = fmaxf(fmaf(c1.z, inv_b, g1.z), 0.f);
                float h7 = fmaxf(fmaf(c1.w, inv_b, g1.w), 0.f);
                sq = fmaf(h0,h0,sq); sq = fmaf(h1,h1,sq);
                sq = fmaf(h2,h2,sq); sq = fmaf(h3,h3,sq);
                sq = fmaf(h4,h4,sq); sq = fmaf(h5,h5,sq);
                sq = fmaf(h6,h6,sq); sq = fmaf(h7,h7,sq);
                dst[v*2+0] = pack2bf(h0,h1);
                dst[v*2+1] = pack2bf(h2,h3);
                dst[v*2+2] = pack2bf(h4,h5);
                dst[v*2+3] = pack2bf(h6,h7);
            }
        }
        { // B stage: W2h rows (n0+r), 32 bf16 per thread
            int r = t >> 1;
            const uint4* s4 = (const uint4*)(W2h + (size_t)(n0 + r) * NH1 + k0 + seg * 32);
            uint4* d = (uint4*)&Bs[r][seg * 32];
            d[0] = s4[0]; d[1] = s4[1]; d[2] = s4[2]; d[3] = s4[3];
        }
        __syncthreads();
#pragma unroll
        for (int kk = 0; kk < 64; kk += 32) {
            bf16x8 af[4], bfr[4];
#pragma unroll
            for (int mt = 0; mt < 4; mt++)
                af[mt] = *(const bf16x8*)&As[wr*64 + mt*16 + cl][kk + qd*8];
#pragma unroll
            for (int nt = 0; nt < 4; nt++)
                bfr[nt] = *(const bf16x8*)&Bs[wc*64 + nt*16 + cl][kk + qd*8];
#pragma unroll
            for (int mt = 0; mt < 4; mt++)
#pragma unroll
                for (int nt = 0; nt < 4; nt++)
                    acc[mt][nt] = __builtin_amdgcn_mfma_f32_16x16x32_bf16(af[mt], bfr[nt], acc[mt][nt], 0, 0, 0);
        }
        __syncthreads();
    }

    // reduce ||h1||^2 per row (2 partials/row), invnh = 1/(||h1||+eps)
    red[t] = sq;
    __syncthreads();
    if (t < 128) {
        float s = red[2*t] + red[2*t+1];
        invnh[t] = 1.0f / (sqrtf(s) + 1e-8f);
    }
    __syncthreads();

    // epilogue: z = acc*invnh + b2 ; h2 = relu(z) ; q += Wq*h2 (reduce over n)
    float wqv[4], b2v[4];
#pragma unroll
    for (int nt = 0; nt < 4; nt++) {
        int o = n0 + wc*64 + nt*16 + cl;
        wqv[nt] = Wq[o]; b2v[nt] = b2[o];
    }
#pragma unroll
    for (int mt = 0; mt < 4; mt++) {
#pragma unroll
        for (int i = 0; i < 4; i++) {
            int m = wr*64 + mt*16 + qd*4 + i;
            float inh = invnh[m];
            float qp = 0.f;
#pragma unroll
            for (int nt = 0; nt < 4; nt++) {
                float z = fmaf(acc[mt][nt][i], inh, b2v[nt]);
                z = fmaxf(z, 0.f);
                qp = fmaf(z, wqv[nt], qp);
            }
            qp += __shfl_xor(qp, 1, 64);
            qp += __shfl_xor(qp, 2, 64);
            qp += __shfl_xor(qp, 4, 64);
            qp += __shfl_xor(qp, 8, 64);
            if (cl == 0) qred[m][wc] = qp;
        }
    }
    __syncthreads();
    if (t < 128) {
        float qv = qred[t][0] + qred[t][1];
        if (colblk == 0) qv += bq[0];
        int aa = atile * 16 + (t >> 3);
        int bb = btile * 8 + (t & 7);
        atomicAdd(out + (size_t)bb * NA + aa, qv);
    }
}

extern "C" void kernel_launch(void* const* d_in, const int* in_sizes, int n_in,
                              void* d_out, int out_size, void* d_ws, size_t ws_size,
                              hipStream_t stream) {
    const float* states = (const float*)d_in[0];
    const float* W1     = (const float*)d_in[1];
    const float* b1     = (const float*)d_in[2];
    const float* W2     = (const float*)d_in[3];
    const float* b2     = (const float*)d_in[4];
    const float* Wq     = (const float*)d_in[5];
    const float* bq     = (const float*)d_in[6];
    float* out = (float*)d_out;

    char* ws = (char*)d_ws;
    float*          G    = (float*)ws;                                    // 16 MB
    unsigned short* W2h  = (unsigned short*)(ws + (16u << 20));           // 1 MB
    float*          caT  = (float*)(ws + (17u << 20));                    // 256 KB
    float*          invn = (float*)(ws + (17u << 20) + (256u << 10));     // 16 KB

    hipMemsetAsync(d_out, 0, (size_t)out_size * sizeof(float), stream);
    knorm<<<NB, 64, 0, stream>>>(states, invn);
    kprep<<<(NH2 * NH1 + NA * NH1) / 256, 256, 0, stream>>>(W1, W2, W2h, caT);
    kgemm1<<<256, 256, 0, stream>>>(states, W1, b1, invn, G);
    kmain<<<8192, 256, 0, stream>>>(G, caT, W2h, invn, b2, Wq, bq, out);
}

// Round 2
// 466.505 us; speedup vs baseline: 2.0625x; 2.0625x over previous
//
#include <hip/hip_runtime.h>
#include <stdint.h>

#define NB 4096
#define NS 512
#define NA 64
#define NH1 1024
#define NH2 512

typedef __attribute__((ext_vector_type(8))) short bf16x8;
typedef __attribute__((ext_vector_type(4))) float f32x4;

__device__ __forceinline__ unsigned short f2bf(float f) {
    union { float f; unsigned u; } v; v.f = f;
    return (unsigned short)((v.u + 0x8000u) >> 16);   // round-half-up bf16
}
__device__ __forceinline__ float bf2f(unsigned short h) {
    union { float f; unsigned u; } v; v.u = ((unsigned)h) << 16;
    return v.f;
}
__device__ __forceinline__ unsigned pack2bf(float lo, float hi) {
    union { float f; unsigned u; } a, b; a.f = lo; b.f = hi;
    unsigned l = (a.u + 0x8000u) >> 16;
    unsigned h = (b.u + 0x8000u) & 0xFFFF0000u;
    return h | l;
}
__device__ __forceinline__ void split2(float x, unsigned short& h, unsigned short& l) {
    unsigned short hh = f2bf(x);
    h = hh;
    l = f2bf(x - bf2f(hh));
}
__device__ __forceinline__ void async_copy16(const void* g, void* l) {
    __builtin_amdgcn_global_load_lds((const __attribute__((address_space(1))) void*)g,
                                     (__attribute__((address_space(3))) void*)l, 16, 0, 0);
}

// ---------------- P0: invn[b] = 1/(sqrt(||s_b||^2 + 1) + 1e-8) ----------------
__global__ void knorm(const float* __restrict__ S, float* __restrict__ invn) {
    int b = blockIdx.x; int l = threadIdx.x; // 64 threads (one wave)
    const float* row = S + b * NS;
    float s = 0.f;
    for (int k = l; k < NS; k += 64) { float v = row[k]; s = fmaf(v, v, s); }
    for (int off = 32; off; off >>= 1) s += __shfl_down(s, off, 64);
    if (l == 0) invn[b] = 1.0f / (sqrtf(s + 1.0f) + 1e-8f);
}

// ---------------- P1: W2 -> swizzled bf16 tiles, caL[at][k][a16] ----------------
// W2t layout: tile (cb in 0..1, kb in 0..15) is 256 rows x 64 shorts, contiguous;
// within a row, 8-short group g stored at slot g' = g ^ (row & 7)  (XOR swizzle).
__global__ void kprep(const float* __restrict__ W1, const float* __restrict__ W2,
                      unsigned short* __restrict__ W2t, float* __restrict__ caL) {
    int i = blockIdx.x * 256 + threadIdx.x;
    if (i < 65536) {
        int gp  = i & 7;            // g' (stored slot)
        int row = (i >> 3) & 255;
        int kb  = (i >> 11) & 15;
        int cb  = i >> 15;
        int o = cb * 256 + row;
        int k = kb * 64 + ((gp ^ (row & 7)) << 3);   // source group g = g'^(row&7)
        const float* src = W2 + (size_t)o * NH1 + k;
        unsigned short* dst = W2t + ((size_t)i << 3);
#pragma unroll
        for (int j = 0; j < 8; j++) dst[j] = f2bf(src[j]);
    } else {
        int j = i - 65536;           // caL index: (at*1024 + k)*16 + a
        int a = j & 15;
        int k = (j >> 4) & 1023;
        int at = j >> 14;
        caL[j] = W1[(size_t)k * 576 + 512 + at * 16 + a];
    }
}

// ---------------- P2: G[b][o] = (states @ W1s^T)*invn_b + b1  (split-bf16, 3 GEMMs) ----
__global__ __launch_bounds__(256) void kgemm1(
        const float* __restrict__ Sm, const float* __restrict__ W1,
        const float* __restrict__ b1, const float* __restrict__ invn,
        float* __restrict__ G) {
    // M=4096(b) x N=1024(o), K=512. 128x128 tiles -> 32x8 = 256 blocks.
    const int m0 = (blockIdx.x >> 3) * 128;
    const int n0 = (blockIdx.x & 7) * 128;
    __shared__ unsigned short Ah[128][40], Al[128][40], Bh[128][40], Bl[128][40];
    int t = threadIdx.x;
    int lane = t & 63, wave = t >> 6;
    int wr = wave >> 1, wc = wave & 1;
    int qd = lane >> 4, cl = lane & 15;
    int r = t >> 1, seg = t & 1;
    f32x4 acc[4][4] = {};

    for (int k0 = 0; k0 < 512; k0 += 32) {
        {
            const float4* as4 = (const float4*)(Sm + (size_t)(m0 + r) * NS + k0 + seg * 16);
            const float4* bs4 = (const float4*)(W1 + (size_t)(n0 + r) * 576 + k0 + seg * 16);
            unsigned* ah = (unsigned*)&Ah[r][seg * 16];
            unsigned* al = (unsigned*)&Al[r][seg * 16];
            unsigned* bh = (unsigned*)&Bh[r][seg * 16];
            unsigned* bl = (unsigned*)&Bl[r][seg * 16];
#pragma unroll
            for (int v = 0; v < 4; v++) {
                float4 fa = as4[v];
                unsigned short h0,h1,h2,h3,l0,l1,l2,l3;
                split2(fa.x,h0,l0); split2(fa.y,h1,l1); split2(fa.z,h2,l2); split2(fa.w,h3,l3);
                ah[v*2]   = (unsigned)h0 | ((unsigned)h1 << 16);
                ah[v*2+1] = (unsigned)h2 | ((unsigned)h3 << 16);
                al[v*2]   = (unsigned)l0 | ((unsigned)l1 << 16);
                al[v*2+1] = (unsigned)l2 | ((unsigned)l3 << 16);
                float4 fb = bs4[v];
                split2(fb.x,h0,l0); split2(fb.y,h1,l1); split2(fb.z,h2,l2); split2(fb.w,h3,l3);
                bh[v*2]   = (unsigned)h0 | ((unsigned)h1 << 16);
                bh[v*2+1] = (unsigned)h2 | ((unsigned)h3 << 16);
                bl[v*2]   = (unsigned)l0 | ((unsigned)l1 << 16);
                bl[v*2+1] = (unsigned)l2 | ((unsigned)l3 << 16);
            }
        }
        __syncthreads();
        bf16x8 a_h[4], a_l[4], b_h[4], b_l[4];
#pragma unroll
        for (int mt = 0; mt < 4; mt++) {
            a_h[mt] = *(const bf16x8*)&Ah[wr*64 + mt*16 + cl][qd*8];
            a_l[mt] = *(const bf16x8*)&Al[wr*64 + mt*16 + cl][qd*8];
        }
#pragma unroll
        for (int nt = 0; nt < 4; nt++) {
            b_h[nt] = *(const bf16x8*)&Bh[wc*64 + nt*16 + cl][qd*8];
            b_l[nt] = *(const bf16x8*)&Bl[wc*64 + nt*16 + cl][qd*8];
        }
#pragma unroll
        for (int mt = 0; mt < 4; mt++)
#pragma unroll
            for (int nt = 0; nt < 4; nt++) {
                acc[mt][nt] = __builtin_amdgcn_mfma_f32_16x16x32_bf16(a_h[mt], b_h[nt], acc[mt][nt], 0, 0, 0);
                acc[mt][nt] = __builtin_amdgcn_mfma_f32_16x16x32_bf16(a_h[mt], b_l[nt], acc[mt][nt], 0, 0, 0);
                acc[mt][nt] = __builtin_amdgcn_mfma_f32_16x16x32_bf16(a_l[mt], b_h[nt], acc[mt][nt], 0, 0, 0);
            }
        __syncthreads();
    }
#pragma unroll
    for (int mt = 0; mt < 4; mt++)
#pragma unroll
        for (int i = 0; i < 4; i++) {
            int m = m0 + wr*64 + mt*16 + qd*4 + i;
            float iv = invn[m];
#pragma unroll
            for (int nt = 0; nt < 4; nt++) {
                int n = n0 + wc*64 + nt*16 + cl;
                G[(size_t)m * NH1 + n] = fmaf(acc[mt][nt][i], iv, b1[n]);
            }
        }
}

// ---------------- Main: rows=(16a x 8b), cols=256 of H2, K=1024 ----------------
// grid 4096 = (512 btile x 4 atile) x 2 colblk; 256 threads; waves 2x2, wave tile 64x128.
__global__ __launch_bounds__(256, 2) void kmain(
        const float* __restrict__ G, const float* __restrict__ caL,
        const unsigned short* __restrict__ W2t, const float* __restrict__ invn,
        const float* __restrict__ b2, const float* __restrict__ Wq,
        const float* __restrict__ bq, float* __restrict__ out) {
    int bid = blockIdx.x;
    int colblk = bid & 1;
    int rt = bid >> 1;
    int atile = rt & 3;
    int btile = rt >> 2;

    __shared__ unsigned short As[128][72];     // row = a_local*8 + b_local, pad=+8 shorts
    __shared__ unsigned short Bs[256 * 64];    // XOR-swizzled, unpadded (global_load_lds dst)
    __shared__ float sqarr[128];
    __shared__ float invnh[128];
    __shared__ float qred[128][2];

    int t = threadIdx.x;
    int lane = t & 63, wave = t >> 6;
    int wr = wave >> 1, wc = wave & 1;
    int qd = lane >> 4, cl = lane & 15;

    // A-gen mapping: thread = (b_local = t&7, kg = t>>3); owns k = k0+2kg, k0+2kg+1 for all 16 a
    int bl = t & 7;
    int kg = t >> 3;                 // 0..31
    int bidx = btile * 8 + bl;
    float invb = invn[bidx];
    const float* grow = G + (size_t)bidx * NH1;
    const float* cabase = caL + ((size_t)atile * NH1) * 16;

    if (t < 128) sqarr[t] = 0.f;

    float sq[16];
#pragma unroll
    for (int a = 0; a < 16; a++) sq[a] = 0.f;

    f32x4 acc[4][8] = {};

    const char* gB = (const char*)W2t + ((size_t)colblk << 19);  // colblk * 16 tiles * 32 KB
    char* lB = (char*)Bs;

    for (int k0 = 0; k0 < NH1; k0 += 64) {
        // ---- B stage: async copy 32 KB swizzled tile (wave-uniform LDS base + lane*16)
        {
            const char* gsrc = gB + ((size_t)(k0 >> 6) << 15) + wave * 8192 + (lane << 4);
            char* ldst = lB + wave * 8192;
#pragma unroll
            for (int i = 0; i < 8; i++)
                async_copy16(gsrc + i * 1024, ldst + i * 1024);
        }
        // ---- A gen: h1 = relu(G + ca*invn), coalesced G float2 + broadcast caL reads
        {
            float2 g2 = *(const float2*)(grow + k0 + 2 * kg);
            const float4* ca0 = (const float4*)(cabase + (size_t)(k0 + 2 * kg) * 16);
            const float4* ca1 = ca0 + 4;   // next k row (+16 floats)
            unsigned* asD = (unsigned*)As;
            int wb = bl * 36 + kg;         // dword base within As for (row=b) offset
#pragma unroll
            for (int c = 0; c < 4; c++) {
                float4 c0 = ca0[c];
                float4 c1 = ca1[c];
                float hx0 = fmaxf(fmaf(c0.x, invb, g2.x), 0.f);
                float hx1 = fmaxf(fmaf(c1.x, invb, g2.y), 0.f);
                float hy0 = fmaxf(fmaf(c0.y, invb, g2.x), 0.f);
                float hy1 = fmaxf(fmaf(c1.y, invb, g2.y), 0.f);
                float hz0 = fmaxf(fmaf(c0.z, invb, g2.x), 0.f);
                float hz1 = fmaxf(fmaf(c1.z, invb, g2.y), 0.f);
                float hw0 = fmaxf(fmaf(c0.w, invb, g2.x), 0.f);
                float hw1 = fmaxf(fmaf(c1.w, invb, g2.y), 0.f);
                sq[4*c+0] = fmaf(hx0, hx0, fmaf(hx1, hx1, sq[4*c+0]));
                sq[4*c+1] = fmaf(hy0, hy0, fmaf(hy1, hy1, sq[4*c+1]));
                sq[4*c+2] = fmaf(hz0, hz0, fmaf(hz1, hz1, sq[4*c+2]));
                sq[4*c+3] = fmaf(hw0, hw0, fmaf(hw1, hw1, sq[4*c+3]));
                asD[(4*c+0)*288 + wb] = pack2bf(hx0, hx1);
                asD[(4*c+1)*288 + wb] = pack2bf(hy0, hy1);
                asD[(4*c+2)*288 + wb] = pack2bf(hz0, hz1);
                asD[(4*c+3)*288 + wb] = pack2bf(hw0, hw1);
            }
        }
        __syncthreads();
        // ---- MFMA: wave tile 64 rows x 128 cols
#pragma unroll
        for (int kk = 0; kk < 64; kk += 32) {
            bf16x8 af[4], bfr[8];
#pragma unroll
            for (int mt = 0; mt < 4; mt++)
                af[mt] = *(const bf16x8*)&As[wr*64 + mt*16 + cl][kk + qd*8];
            int gg = qd + (kk >> 3);
#pragma unroll
            for (int nt = 0; nt < 8; nt++) {
                int rw = wc*128 + nt*16 + cl;
                bfr[nt] = *(const bf16x8*)&Bs[rw*64 + ((gg ^ (rw & 7)) << 3)];
            }
#pragma unroll
            for (int mt = 0; mt < 4; mt++)
#pragma unroll
                for (int nt = 0; nt < 8; nt++)
                    acc[mt][nt] = __builtin_amdgcn_mfma_f32_16x16x32_bf16(af[mt], bfr[nt], acc[mt][nt], 0, 0, 0);
        }
        __syncthreads();
    }

    // ---- ||h1||^2: in-wave shuffle over kg, cross-wave via LDS atomics
#pragma unroll
    for (int a = 0; a < 16; a++) {
        float s = sq[a];
        s += __shfl_xor(s, 8, 64);
        s += __shfl_xor(s, 16, 64);
        s += __shfl_xor(s, 32, 64);
        if (lane < 8) atomicAdd(&sqarr[a*8 + lane], s);
    }
    __syncthreads();
    if (t < 128) invnh[t] = 1.0f / (sqrtf(sqarr[t]) + 1e-8f);
    __syncthreads();

    // ---- epilogue: z = acc*invnh + b2; h2 = relu(z); q = sum(Wq*h2)
    float wqv[8], b2v[8];
#pragma unroll
    for (int nt = 0; nt < 8; nt++) {
        int o = colblk*256 + wc*128 + nt*16 + cl;
        wqv[nt] = Wq[o]; b2v[nt] = b2[o];
    }
#pragma unroll
    for (int mt = 0; mt < 4; mt++) {
#pragma unroll
        for (int i = 0; i < 4; i++) {
            int m = wr*64 + mt*16 + qd*4 + i;
            float inh = invnh[m];
            float qp = 0.f;
#pragma unroll
            for (int nt = 0; nt < 8; nt++) {
                float z = fmaf(acc[mt][nt][i], inh, b2v[nt]);
                z = fmaxf(z, 0.f);
                qp = fmaf(z, wqv[nt], qp);
            }
            qp += __shfl_xor(qp, 1, 64);
            qp += __shfl_xor(qp, 2, 64);
            qp += __shfl_xor(qp, 4, 64);
            qp += __shfl_xor(qp, 8, 64);
            if (cl == 0) qred[m][wc] = qp;
        }
    }
    __syncthreads();
    if (t < 128) {
        float qv = qred[t][0] + qred[t][1];
        if (colblk == 0) qv += bq[0];
        int aa = atile*16 + (t >> 3);
        int bb = btile*8 + (t & 7);
        atomicAdd(out + (size_t)bb * NA + aa, qv);
    }
}

extern "C" void kernel_launch(void* const* d_in, const int* in_sizes, int n_in,
                              void* d_out, int out_size, void* d_ws, size_t ws_size,
                              hipStream_t stream) {
    const float* states = (const float*)d_in[0];
    const float* W1     = (const float*)d_in[1];
    const float* b1     = (const float*)d_in[2];
    const float* W2     = (const float*)d_in[3];
    const float* b2     = (const float*)d_in[4];
    const float* Wq     = (const float*)d_in[5];
    const float* bq     = (const float*)d_in[6];
    float* out = (float*)d_out;

    char* ws = (char*)d_ws;
    float*          G    = (float*)ws;                                    // 16 MB
    unsigned short* W2t  = (unsigned short*)(ws + (16u << 20));           // 1 MB (swizzled tiles)
    float*          caL  = (float*)(ws + (17u << 20));                    // 256 KB [at][k][a16]
    float*          invn = (float*)(ws + (17u << 20) + (256u << 10));     // 16 KB

    hipMemsetAsync(d_out, 0, (size_t)out_size * sizeof(float), stream);
    knorm<<<NB, 64, 0, stream>>>(states, invn);
    kprep<<<512, 256, 0, stream>>>(W1, W2, W2t, caL);
    kgemm1<<<256, 256, 0, stream>>>(states, W1, b1, invn, G);
    kmain<<<4096, 256, 0, stream>>>(G, caL, W2t, invn, b2, Wq, bq, out);
}

// Round 3
// 454.769 us; speedup vs baseline: 2.1157x; 1.0258x over previous
//
#include <hip/hip_runtime.h>
#include <stdint.h>

#define NB 4096
#define NS 512
#define NA 64
#define NH1 1024
#define NH2 512

typedef __attribute__((ext_vector_type(8))) short bf16x8;
typedef __attribute__((ext_vector_type(4))) float f32x4;

__device__ __forceinline__ unsigned short f2bf(float f) {
    union { float f; unsigned u; } v; v.f = f;
    return (unsigned short)((v.u + 0x8000u) >> 16);   // round-half-up bf16
}
__device__ __forceinline__ float bf2f(unsigned short h) {
    union { float f; unsigned u; } v; v.u = ((unsigned)h) << 16;
    return v.f;
}
__device__ __forceinline__ float bflo(unsigned u) {
    union { unsigned u; float f; } v; v.u = u << 16; return v.f;
}
__device__ __forceinline__ float bfhi(unsigned u) {
    union { unsigned u; float f; } v; v.u = u & 0xFFFF0000u; return v.f;
}
// pack two fp32 -> bf16x2 dword (round-half-up) via v_perm_b32: 3 VALU ops
__device__ __forceinline__ unsigned packrnd(float lo, float hi) {
    union { float f; unsigned u; } a, b; a.f = lo; b.f = hi;
    return __builtin_amdgcn_perm(b.u + 0x8000u, a.u + 0x8000u, 0x07060302u);
}
__device__ __forceinline__ void split2(float x, unsigned short& h, unsigned short& l) {
    unsigned short hh = f2bf(x);
    h = hh;
    l = f2bf(x - bf2f(hh));
}
__device__ __forceinline__ void async_copy16(const void* g, void* l) {
    __builtin_amdgcn_global_load_lds((const __attribute__((address_space(1))) void*)g,
                                     (__attribute__((address_space(3))) void*)l, 16, 0, 0);
}

// ---------------- P0: invn[b] = 1/(sqrt(||s_b||^2 + 1) + 1e-8) ----------------
__global__ void knorm(const float* __restrict__ S, float* __restrict__ invn) {
    int b = blockIdx.x; int l = threadIdx.x; // 64 threads (one wave)
    const float* row = S + b * NS;
    float s = 0.f;
    for (int k = l; k < NS; k += 64) { float v = row[k]; s = fmaf(v, v, s); }
    for (int off = 32; off; off >>= 1) s += __shfl_down(s, off, 64);
    if (l == 0) invn[b] = 1.0f / (sqrtf(s + 1.0f) + 1e-8f);
}

// ---------------- P1: build W2f (DMA-frag-packed, XOR-swizzled) + caT2 ----------------
// W2f shorts, frag f = ((cb*16+kb)*16 + c)*64 + l holds
//   W2[n = cb*128 + c*8 + (l>>3)][k = kb*64 + (((l&7)^((l>>3)&7))<<3) + j]
// caT2: [at][kb][a 0..31][k 0..63] bf16, value = W1[(kb*64+kk)*576 + 512 + at*32 + a]
__global__ void kprep(const float* __restrict__ W1, const float* __restrict__ W2,
                      unsigned short* __restrict__ W2f, unsigned short* __restrict__ caT2) {
    int i = blockIdx.x * 256 + threadIdx.x;
    if (i < 524288) {
        int j = i & 7; int f = i >> 3;
        int l = f & 63; int c = (f >> 6) & 15; int kb = (f >> 10) & 15; int cbb = f >> 14;
        int n = cbb * 128 + c * 8 + (l >> 3);
        int k = kb * 64 + (((l & 7) ^ ((l >> 3) & 7)) << 3) + j;
        W2f[i] = f2bf(W2[(size_t)n * NH1 + k]);
    } else {
        int j = i - 524288;           // 65536 entries
        int kk = j & 63; int a = (j >> 6) & 31; int kb = (j >> 11) & 15; int att = j >> 15;
        int o = kb * 64 + kk;
        caT2[j] = f2bf(W1[(size_t)o * 576 + 512 + att * 32 + a]);
    }
}

// ---------------- P2: Gt[kb][b][64k] bf16 = ((states @ W1s^T)*invn_b + b1), split-bf16 ----
__global__ __launch_bounds__(256) void kgemm1(
        const float* __restrict__ Sm, const float* __restrict__ W1,
        const float* __restrict__ b1, const float* __restrict__ invn,
        unsigned short* __restrict__ Gt) {
    const int m0 = (blockIdx.x >> 3) * 128;
    const int n0 = (blockIdx.x & 7) * 128;
    __shared__ unsigned short Ah[128][40], Al[128][40], Bh[128][40], Bl[128][40];
    int t = threadIdx.x;
    int lane = t & 63, wave = t >> 6;
    int wr = wave >> 1, wc = wave & 1;
    int qd = lane >> 4, cl = lane & 15;
    int r = t >> 1, seg = t & 1;
    f32x4 acc[4][4] = {};

    for (int k0 = 0; k0 < 512; k0 += 32) {
        {
            const float4* as4 = (const float4*)(Sm + (size_t)(m0 + r) * NS + k0 + seg * 16);
            const float4* bs4 = (const float4*)(W1 + (size_t)(n0 + r) * 576 + k0 + seg * 16);
            unsigned* ah = (unsigned*)&Ah[r][seg * 16];
            unsigned* al = (unsigned*)&Al[r][seg * 16];
            unsigned* bh = (unsigned*)&Bh[r][seg * 16];
            unsigned* bl = (unsigned*)&Bl[r][seg * 16];
#pragma unroll
            for (int v = 0; v < 4; v++) {
                float4 fa = as4[v];
                unsigned short h0,h1,h2,h3,l0,l1,l2,l3;
                split2(fa.x,h0,l0); split2(fa.y,h1,l1); split2(fa.z,h2,l2); split2(fa.w,h3,l3);
                ah[v*2]   = (unsigned)h0 | ((unsigned)h1 << 16);
                ah[v*2+1] = (unsigned)h2 | ((unsigned)h3 << 16);
                al[v*2]   = (unsigned)l0 | ((unsigned)l1 << 16);
                al[v*2+1] = (unsigned)l2 | ((unsigned)l3 << 16);
                float4 fb = bs4[v];
                split2(fb.x,h0,l0); split2(fb.y,h1,l1); split2(fb.z,h2,l2); split2(fb.w,h3,l3);
                bh[v*2]   = (unsigned)h0 | ((unsigned)h1 << 16);
                bh[v*2+1] = (unsigned)h2 | ((unsigned)h3 << 16);
                bl[v*2]   = (unsigned)l0 | ((unsigned)l1 << 16);
                bl[v*2+1] = (unsigned)l2 | ((unsigned)l3 << 16);
            }
        }
        __syncthreads();
        bf16x8 a_h[4], a_l[4], b_h[4], b_l[4];
#pragma unroll
        for (int mt = 0; mt < 4; mt++) {
            a_h[mt] = *(const bf16x8*)&Ah[wr*64 + mt*16 + cl][qd*8];
            a_l[mt] = *(const bf16x8*)&Al[wr*64 + mt*16 + cl][qd*8];
        }
#pragma unroll
        for (int nt = 0; nt < 4; nt++) {
            b_h[nt] = *(const bf16x8*)&Bh[wc*64 + nt*16 + cl][qd*8];
            b_l[nt] = *(const bf16x8*)&Bl[wc*64 + nt*16 + cl][qd*8];
        }
#pragma unroll
        for (int mt = 0; mt < 4; mt++)
#pragma unroll
            for (int nt = 0; nt < 4; nt++) {
                acc[mt][nt] = __builtin_amdgcn_mfma_f32_16x16x32_bf16(a_h[mt], b_h[nt], acc[mt][nt], 0, 0, 0);
                acc[mt][nt] = __builtin_amdgcn_mfma_f32_16x16x32_bf16(a_h[mt], b_l[nt], acc[mt][nt], 0, 0, 0);
                acc[mt][nt] = __builtin_amdgcn_mfma_f32_16x16x32_bf16(a_l[mt], b_h[nt], acc[mt][nt], 0, 0, 0);
            }
        __syncthreads();
    }
#pragma unroll
    for (int mt = 0; mt < 4; mt++)
#pragma unroll
        for (int i = 0; i < 4; i++) {
            int m = m0 + wr*64 + mt*16 + qd*4 + i;
            float iv = invn[m];
#pragma unroll
            for (int nt = 0; nt < 4; nt++) {
                int n = n0 + wc*64 + nt*16 + cl;
                float val = fmaf(acc[mt][nt][i], iv, b1[n]);
                Gt[((size_t)(n >> 6) * NB + m) * 64 + (n & 63)] = f2bf(val);
            }
        }
}

// ---------------- Main: 1-barrier dbuf pipeline, reg-A, 256rows x 128cols / block ----
// grid 4096 = (512 bt x 2 at) x 4 cb. 4 waves stacked in M (wave = 64 rows = 8a x 8b).
__global__ __launch_bounds__(256, 2) void kmain(
        const unsigned short* __restrict__ Gt,    // [16][4096][64]
        const unsigned short* __restrict__ caT2,  // [2][16][32][64]
        const unsigned short* __restrict__ W2f,   // frag-packed, swizzled
        const float* __restrict__ invn,
        const float* __restrict__ b2, const float* __restrict__ Wq,
        const float* __restrict__ bq, float* __restrict__ out) {
    int bid = blockIdx.x;
    int cb = bid & 3;
    int rt = bid >> 2;
    int at = rt & 1;
    int bt = rt >> 1;

    // slot: [B 16384 | G 1024 | CA 4096] = 21504 B
    __shared__ __align__(16) char smem[2][21504];

    int t = threadIdx.x;
    int lane = t & 63, w = t >> 6;
    int l15 = lane & 15, l4 = lane >> 4;
    int bl = lane & 7;
    float invb = invn[bt * 8 + bl];

    f32x4 acc[4][8] = {};
    float sqa[4] = {0.f, 0.f, 0.f, 0.f};

    // ---- fill chunks for iteration kb into slot s (wave-distributed) ----
    auto fill = [&](int kb, int s) {
        char* base = smem[s];
        for (int c = w; c < 21; c += 4) {
            const char* gsrc;
            char* ldst;
            if (c < 16) {
                gsrc = (const char*)W2f + ((((size_t)(cb * 16 + kb) * 16 + c) * 64 + lane) << 4);
                ldst = base + c * 1024 + (lane << 4);
            } else if (c == 16) {
                gsrc = (const char*)Gt + (((size_t)kb * NB + bt * 8) * 64) * 2 + (lane << 4);
                ldst = base + 16384 + (lane << 4);
            } else {
                int h = c - 17;
                gsrc = (const char*)caT2 + ((((size_t)(at * 16 + kb) * 32 + h * 8) * 64) * 2) + (lane << 4);
                ldst = base + 17408 + h * 1024 + (lane << 4);
            }
            async_copy16(gsrc, ldst);
        }
    };

    fill(0, 0);

    for (int it = 0; it < 16; ++it) {
        int s = it & 1;
        __syncthreads();              // compiler-inserted vmcnt(0) drains fill(it) (a full iter old)
        if (it < 15) fill(it + 1, s ^ 1);

        const unsigned short* Gs = (const unsigned short*)(smem[s] + 16384);
        const unsigned short* Cs = (const unsigned short*)(smem[s] + 17408);
        const unsigned short* Bsh = (const unsigned short*)(smem[s]);

        // ---- A-gen: h = relu(G + ca*invb), frags in regs, sq accumulated ----
        unsigned afd[2][4][4];
#pragma unroll
        for (int kk2 = 0; kk2 < 2; kk2++) {
            int kk = kk2 * 32;
            bf16x8 gf = *(const bf16x8*)(Gs + bl * 64 + kk + l4 * 8);
            const unsigned* gd = (const unsigned*)&gf;
            float gv[8];
#pragma unroll
            for (int p = 0; p < 4; p++) { gv[2*p] = bflo(gd[p]); gv[2*p+1] = bfhi(gd[p]); }
#pragma unroll
            for (int mt = 0; mt < 4; mt++) {
                int a_loc = w * 8 + mt * 2 + ((lane >> 3) & 1);
                bf16x8 cf = *(const bf16x8*)(Cs + a_loc * 64 + kk + l4 * 8);
                const unsigned* cd = (const unsigned*)&cf;
#pragma unroll
                for (int p = 0; p < 4; p++) {
                    unsigned cu = cd[p];
                    float h0 = fmaxf(fmaf(bflo(cu), invb, gv[2*p]), 0.f);
                    float h1 = fmaxf(fmaf(bfhi(cu), invb, gv[2*p+1]), 0.f);
                    sqa[mt] = fmaf(h0, h0, sqa[mt]);
                    sqa[mt] = fmaf(h1, h1, sqa[mt]);
                    afd[kk2][mt][p] = packrnd(h0, h1);
                }
            }
        }

        // ---- MFMA: wave tile 64 x 128 ----
#pragma unroll
        for (int kk2 = 0; kk2 < 2; kk2++) {
            bf16x8 bfr[8];
#pragma unroll
            for (int nt = 0; nt < 8; nt++) {
                int n = nt * 16 + l15;
                int g = kk2 * 4 + l4;
                bfr[nt] = *(const bf16x8*)(Bsh + n * 64 + ((g ^ (n & 7)) << 3));
            }
#pragma unroll
            for (int mt = 0; mt < 4; mt++) {
                bf16x8 av = *(const bf16x8*)&afd[kk2][mt][0];
#pragma unroll
                for (int nt = 0; nt < 8; nt++)
                    acc[mt][nt] = __builtin_amdgcn_mfma_f32_16x16x32_bf16(av, bfr[nt], acc[mt][nt], 0, 0, 0);
            }
        }
    }

    // ---- epilogue: norm, relu, Wq-dot, atomic accumulate ----
    float invr[4];
#pragma unroll
    for (int mt = 0; mt < 4; mt++) {
        float sv = sqa[mt];
        sv += __shfl_xor(sv, 16, 64);
        sv += __shfl_xor(sv, 32, 64);
        invr[mt] = 1.0f / (sqrtf(sv) + 1e-8f);   // valid for row mt*16 + l15
    }
    float wqv[8], b2v[8];
#pragma unroll
    for (int nt = 0; nt < 8; nt++) {
        int o = cb * 128 + nt * 16 + l15;
        wqv[nt] = Wq[o]; b2v[nt] = b2[o];
    }
    float bqv = (cb == 0) ? bq[0] : 0.f;
#pragma unroll
    for (int mt = 0; mt < 4; mt++) {
#pragma unroll
        for (int i = 0; i < 4; i++) {
            int rloc = l4 * 4 + i;                        // C/D row within 16-tile
            float inv = __shfl(invr[mt], rloc, 64);       // lane rloc holds row mt*16+rloc
            float qp = 0.f;
#pragma unroll
            for (int nt = 0; nt < 8; nt++) {
                float z = fmaf(acc[mt][nt][i], inv, b2v[nt]);
                z = fmaxf(z, 0.f);
                qp = fmaf(z, wqv[nt], qp);
            }
            qp += __shfl_xor(qp, 1, 64);
            qp += __shfl_xor(qp, 2, 64);
            qp += __shfl_xor(qp, 4, 64);
            qp += __shfl_xor(qp, 8, 64);
            if (l15 == 0) {
                int R = w * 64 + mt * 16 + rloc;
                int aa = at * 32 + (R >> 3);
                int bb = bt * 8 + (R & 7);
                atomicAdd(out + (size_t)bb * NA + aa, qp + bqv);
            }
        }
    }
}

extern "C" void kernel_launch(void* const* d_in, const int* in_sizes, int n_in,
                              void* d_out, int out_size, void* d_ws, size_t ws_size,
                              hipStream_t stream) {
    const float* states = (const float*)d_in[0];
    const float* W1     = (const float*)d_in[1];
    const float* b1     = (const float*)d_in[2];
    const float* W2     = (const float*)d_in[3];
    const float* b2     = (const float*)d_in[4];
    const float* Wq     = (const float*)d_in[5];
    const float* bq     = (const float*)d_in[6];
    float* out = (float*)d_out;

    char* ws = (char*)d_ws;
    unsigned short* Gt   = (unsigned short*)ws;                              // 8 MB
    unsigned short* W2f  = (unsigned short*)(ws + (8u << 20));               // 1 MB
    unsigned short* caT2 = (unsigned short*)(ws + (9u << 20));               // 128 KB
    float*          invn = (float*)(ws + (9u << 20) + (128u << 10));         // 16 KB

    hipMemsetAsync(d_out, 0, (size_t)out_size * sizeof(float), stream);
    knorm<<<NB, 64, 0, stream>>>(states, invn);
    kprep<<<2304, 256, 0, stream>>>(W1, W2, W2f, caT2);
    kgemm1<<<256, 256, 0, stream>>>(states, W1, b1, invn, Gt);
    kmain<<<4096, 256, 0, stream>>>(Gt, caT2, W2f, invn, b2, Wq, bq, out);
}